// Round 12
// baseline (458.466 us; speedup 1.0000x reference)
//
#include <hip/hip_runtime.h>
#include <math.h>

#define NN 8192
#define FF 256
#define ALPHA 0.2f
#define SS 8                 // j-segments
#define JSEG (NN / SS)       // 1024
#define STEPS (JSEG / 32)    // 32 steps of 32 j each (even)
#define BI 128               // i-rows per k3 block (4 waves x 32 rows)

typedef __bf16 bf16x8 __attribute__((ext_vector_type(8)));
typedef __bf16 bf16x4 __attribute__((ext_vector_type(4)));
typedef float  f32x4  __attribute__((ext_vector_type(4)));

__device__ __forceinline__ void dma16(const void* g, void* l) {
    __builtin_amdgcn_global_load_lds((const __attribute__((address_space(1))) void*)g,
                                     (__attribute__((address_space(3))) void*)l,
                                     16, 0, 0);
}

#define VMCNT0   asm volatile("s_waitcnt vmcnt(0)" ::: "memory")
#define LGKM0    asm volatile("s_waitcnt lgkmcnt(0)" ::: "memory")
#define BARRIER  asm volatile("s_barrier" ::: "memory")
#define FENCE    asm volatile("" ::: "memory")

// ---------------- K02a: fused W->WT convert (blocks 0..15) + adj pack -----
// Independent work, block-range split: saves one ~13us dispatch.
__global__ __launch_bounds__(256) void k02a(const float* __restrict__ W,
                                            __bf16* __restrict__ WT,
                                            const int* __restrict__ adj,
                                            unsigned* __restrict__ bits,
                                            unsigned* __restrict__ maxd) {
    __shared__ float ts[64][65];
    const int t = threadIdx.x;
    if (blockIdx.x < 16) {
        // ---- k0 body: WT[hl][n][k] bf16 hi/lo from W[k][n] fp32 ----
        const int k0 = (blockIdx.x & 3) * 64;
        const int n0 = (blockIdx.x >> 2) * 64;
        #pragma unroll
        for (int r = 0; r < 4; ++r) {
            int krow = r * 16 + (t >> 4);
            int nc4 = (t & 15) * 4;
            *(float4*)&ts[krow][nc4] = *(const float4*)&W[(size_t)(k0 + krow) * FF + n0 + nc4];
        }
        __syncthreads();
        const int nloc = t >> 2;
        const int kc = (t & 3) * 16;
        union { bf16x8 v[2]; __bf16 e[16]; } hi, lo;
        #pragma unroll
        for (int u = 0; u < 16; ++u) {
            float x = ts[kc + u][nloc];
            __bf16 h1 = (__bf16)x;
            hi.e[u] = h1;
            lo.e[u] = (__bf16)(x - (float)h1);
        }
        size_t base = (size_t)(n0 + nloc) * FF + k0 + kc;
        *(bf16x8*)&WT[base] = hi.v[0];
        *(bf16x8*)&WT[base + 8] = hi.v[1];
        size_t lbase = (size_t)FF * FF + base;
        *(bf16x8*)&WT[lbase] = lo.v[0];
        *(bf16x8*)&WT[lbase + 8] = lo.v[1];
        return;
    }
    // ---- k2a body: pack adj int32 -> 1 bit/elem; init maxd ----
    if (blockIdx.x == 16 && t == 0) maxd[0] = 0u;   // key of -inf
    const size_t total4 = (size_t)NN * NN / 4;
    const int l = t & 63;
    const int base = l & 56;
    size_t p = (size_t)(blockIdx.x - 16) * 256 + t;
    const size_t stride = (size_t)(gridDim.x - 16) * 256;
    for (; p < total4; p += stride) {
        int4 v = ((const int4*)adj)[p];
        unsigned nib = (unsigned)(v.x > 0) | ((unsigned)(v.y > 0) << 1)
                     | ((unsigned)(v.z > 0) << 2) | ((unsigned)(v.w > 0) << 3);
        unsigned w = 0;
        #pragma unroll
        for (int k = 0; k < 8; ++k)
            w |= (unsigned)__shfl((int)nib, base + k) << (4 * k);
        if ((l & 7) == 0)
            bits[p >> 3] = w;
    }
}

// ---------------- K1: MFMA h-tile -> hT(seg-major) + src/dst + maxd -------
__global__ __launch_bounds__(256) void k1_h(const float* __restrict__ X,
                                            const __bf16* __restrict__ WT,
                                            const float* __restrict__ a,
                                            __bf16* __restrict__ hT,
                                            float* __restrict__ src,
                                            float* __restrict__ dst,
                                            unsigned* __restrict__ maxd) {
    __shared__ __bf16 ax[2][32][40];
    __shared__ float hs[32][264];
    __shared__ float red[2][4][32];
    const int t = threadIdx.x;
    const int i0 = blockIdx.x * 32;
    const int l = t & 63, wv = t >> 6, ln = l & 15, g = l >> 4;
    f32x4 acc[2][4];
    #pragma unroll
    for (int mt = 0; mt < 2; ++mt)
        #pragma unroll
        for (int nt = 0; nt < 4; ++nt)
            acc[mt][nt] = (f32x4){0.f, 0.f, 0.f, 0.f};

    for (int ks = 0; ks < 8; ++ks) {
        const int k0 = ks * 32;
        {
            int row = t >> 3, c4 = (t & 7) * 4;
            float4 xv = *(const float4*)&X[(size_t)(i0 + row) * FF + k0 + c4];
            bf16x4 hi4, lo4;
            float xs_[4] = {xv.x, xv.y, xv.z, xv.w};
            #pragma unroll
            for (int u = 0; u < 4; ++u) {
                __bf16 h1 = (__bf16)xs_[u];
                hi4[u] = h1;
                lo4[u] = (__bf16)(xs_[u] - (float)h1);
            }
            *(bf16x4*)&ax[0][row][c4] = hi4;
            *(bf16x4*)&ax[1][row][c4] = lo4;
        }
        __syncthreads();
        bf16x8 ah[2], al[2];
        ah[0] = *(bf16x8*)&ax[0][ln][g * 8];
        ah[1] = *(bf16x8*)&ax[0][16 + ln][g * 8];
        al[0] = *(bf16x8*)&ax[1][ln][g * 8];
        al[1] = *(bf16x8*)&ax[1][16 + ln][g * 8];
        #pragma unroll
        for (int nt = 0; nt < 4; ++nt) {
            const int n = wv * 64 + nt * 16 + ln;
            bf16x8 bh8 = *(const bf16x8*)&WT[(size_t)n * FF + k0 + g * 8];
            bf16x8 bl8 = *(const bf16x8*)&WT[(size_t)(FF + n) * FF + k0 + g * 8];
            #pragma unroll
            for (int mt = 0; mt < 2; ++mt) {
                acc[mt][nt] = __builtin_amdgcn_mfma_f32_16x16x32_bf16(ah[mt], bh8, acc[mt][nt], 0, 0, 0);
                acc[mt][nt] = __builtin_amdgcn_mfma_f32_16x16x32_bf16(ah[mt], bl8, acc[mt][nt], 0, 0, 0);
                acc[mt][nt] = __builtin_amdgcn_mfma_f32_16x16x32_bf16(al[mt], bh8, acc[mt][nt], 0, 0, 0);
            }
        }
        __syncthreads();
    }
    float an[4], ad[4];
    #pragma unroll
    for (int nt = 0; nt < 4; ++nt) {
        an[nt] = a[wv * 64 + nt * 16 + ln];
        ad[nt] = a[FF + wv * 64 + nt * 16 + ln];
    }
    float sp[2][4], dp[2][4];
    #pragma unroll
    for (int mt = 0; mt < 2; ++mt)
        #pragma unroll
        for (int rg = 0; rg < 4; ++rg) { sp[mt][rg] = 0.f; dp[mt][rg] = 0.f; }
    #pragma unroll
    for (int mt = 0; mt < 2; ++mt)
        #pragma unroll
        for (int nt = 0; nt < 4; ++nt)
            #pragma unroll
            for (int rg = 0; rg < 4; ++rg) {
                float v = acc[mt][nt][rg];
                hs[mt * 16 + g * 4 + rg][wv * 64 + nt * 16 + ln] = v;
                sp[mt][rg] += v * an[nt];
                dp[mt][rg] += v * ad[nt];
            }
    #pragma unroll
    for (int mk = 1; mk < 16; mk <<= 1)
        #pragma unroll
        for (int mt = 0; mt < 2; ++mt)
            #pragma unroll
            for (int rg = 0; rg < 4; ++rg) {
                sp[mt][rg] += __shfl_xor(sp[mt][rg], mk);
                dp[mt][rg] += __shfl_xor(dp[mt][rg], mk);
            }
    if (ln == 0) {
        #pragma unroll
        for (int mt = 0; mt < 2; ++mt)
            #pragma unroll
            for (int rg = 0; rg < 4; ++rg) {
                red[0][wv][mt * 16 + g * 4 + rg] = sp[mt][rg];
                red[1][wv][mt * 16 + g * 4 + rg] = dp[mt][rg];
            }
    }
    __syncthreads();
    if (t < 32) {
        src[i0 + t] = red[0][0][t] + red[0][1][t] + red[0][2][t] + red[0][3][t];
        float dv_ = red[1][0][t] + red[1][1][t] + red[1][2][t] + red[1][3][t];
        dst[i0 + t] = dv_;
        unsigned u = __float_as_uint(dv_);
        unsigned key = (u & 0x80000000u) ? ~u : (u | 0x80000000u);
        atomicMax(maxd, key);
    }
    {
        const int f = t;
        const int seg_i = i0 >> 10;             // i0 / JSEG
        const int ilb = i0 & (JSEG - 1);
        #pragma unroll
        for (int jc = 0; jc < 4; ++jc) {
            union { bf16x8 v; __bf16 e[8]; } hi;
            #pragma unroll
            for (int u = 0; u < 8; ++u) {
                float x = hs[jc * 8 + u][f];
                hi.e[u] = (__bf16)x;
            }
            *(bf16x8*)&hT[((size_t)seg_i * FF + f) * JSEG + ilb + jc * 8] = hi.v;
        }
    }
}

// ---------------- K3: M-replicated MFMA attention (LDS reads halved) ------
// R11 post-mortem: cycle model shows k3 is LDS-read-BW bound (~2048 cyc/step
// of ds_read_b128 vs 320 MFMA + 480 VALU). Fix: each wave holds TWO
// A-fragments (rows wv*32+[0,16) and +[16,32)) and issues TWO MFMAs per
// single B-fragment read -> LDS reads per MFMA halve. acc = 2x16 f32x4 =
// 128 VGPR (~175 total, no spill; 2 blocks/CU, same occupancy as R6's
// verified config). Step skeleton / DMA descriptors / swizzle / seg-major
// hT all from harness-verified rounds (R6/R7/R11).
__global__ __launch_bounds__(256, 2) void k3_attn(const unsigned* __restrict__ bits,
                                                  const __bf16* __restrict__ hT,
                                                  const float* __restrict__ src,
                                                  const float* __restrict__ dst,
                                                  const unsigned* __restrict__ maxd,
                                                  float* __restrict__ num,
                                                  float* __restrict__ den) {
    __shared__ __bf16 bh[2][1024 * 8];      // 32 KB B-tile double buffer
    __shared__ float dsts[JSEG];            // 4 KB dst segment
    const int t = threadIdx.x;
    const int l = t & 63, wv = t >> 6, ln = l & 15, g = l >> 4;
    const int seg = blockIdx.x & 7;         // seg -> XCD affinity
    const int it = blockIdx.x >> 3;         // NN/BI = 64 i-tiles
    const int i0 = it * BI;
    const int jbeg = seg * JSEG;
    const int row0 = i0 + wv * 32 + ln;     // M-rep 0
    const int row1 = row0 + 16;             // M-rep 1
    const unsigned mk_ = maxd[0];
    const float maxdv = (mk_ & 0x80000000u) ? __uint_as_float(mk_ & 0x7fffffffu)
                                            : __uint_as_float(~mk_);
    const float s0 = src[row0];
    const float s1 = src[row1];
    const float e00 = s0 + maxdv;
    const float m0 = e00 > 0.f ? e00 : ALPHA * e00;
    const float e01 = s1 + maxdv;
    const float m1 = e01 > 0.f ? e01 : ALPHA * e01;

    // segment-local B panel (contiguous 512 KB)
    const __bf16* hTs = hT + (size_t)seg * FF * JSEG;

    // DMA descriptors: 4 chunks/thread (1024 chunks), lane-linear LDS,
    // swizzle on gaddr (R7-verified form). Chunk c = f*4+pc holds
    // hTs[f][jl+(pc^((f>>1)&3))*8..+8] at byte c*16.
    int ga[4], cb[4];
    #pragma unroll
    for (int r = 0; r < 4; ++r) {
        int cbase = r * 256 + wv * 64;
        int c = cbase + l;
        int f = c >> 2;
        int pc = c & 3;
        int jc = pc ^ ((f >> 1) & 3);
        ga[r] = f * JSEG + jc * 8;      // seg-local offset
        cb[r] = __builtin_amdgcn_readfirstlane(cbase);
    }
    // B-read base (BYTES): f=nt*16+ln -> elem off = f*32 + (g^sw)*8
    const int rb = ln * 64 + ((g ^ ((ln >> 1) & 3)) * 16);
    const char* bh0 = (const char*)&bh[0][0] + rb;
    const char* bh1 = (const char*)&bh[1][0] + rb;

    // mask sources: word s of each row's segment
    const unsigned* grow0 = bits + (size_t)row0 * (NN / 32) + (jbeg >> 5);
    const unsigned* grow1 = bits + (size_t)row1 * (NN / 32) + (jbeg >> 5);

    // prologue: DMA tile 0 -> bh[0]; dst segment -> LDS; mask pairs -> regs
    #pragma unroll
    for (int r = 0; r < 4; ++r)
        dma16(&hTs[ga[r]], &bh[0][cb[r] * 8]);
    FENCE;
    *(float4*)&dsts[t * 4] = *(const float4*)&dst[jbeg + t * 4];
    uint2 wpa = *(const uint2*)&grow0[0];
    uint2 wpb = *(const uint2*)&grow1[0];
    uint2 wpan = wpa, wpbn = wpb;
    __syncthreads();            // drains vmcnt(0)+lgkmcnt(0)

    float den0 = 0.f, den1 = 0.f;
    f32x4 acc0[16], acc1[16];
    #pragma unroll
    for (int nt = 0; nt < 16; ++nt) {
        acc0[nt] = (f32x4){0.f, 0.f, 0.f, 0.f};
        acc1[nt] = (f32x4){0.f, 0.f, 0.f, 0.f};
    }

#define K3_WCOMP2(S_, MA_, MB_, AF0_, AF1_)                                   \
    {                                                                         \
        unsigned mba = ((MA_) >> (g * 8)) & 0xffu;                            \
        unsigned mbb = ((MB_) >> (g * 8)) & 0xffu;                            \
        const float* dp_ = &dsts[(S_) * 32 + g * 8];                          \
        float4 dq0 = *(const float4*)dp_;                                     \
        float4 dq1 = *(const float4*)(dp_ + 4);                               \
        const float dv[8] = {dq0.x, dq0.y, dq0.z, dq0.w,                      \
                             dq1.x, dq1.y, dq1.z, dq1.w};                     \
        _Pragma("unroll")                                                     \
        for (int u = 0; u < 8; ++u) {                                         \
            float ea = s0 + dv[u];                                            \
            ea = ea > 0.f ? ea : ALPHA * ea;                                  \
            float wa = (mba & (1u << u)) ? __expf(ea - m0) : 0.f;             \
            den0 += wa;                                                       \
            AF0_.e[u] = (__bf16)wa;                                           \
            float eb = s1 + dv[u];                                            \
            eb = eb > 0.f ? eb : ALPHA * eb;                                  \
            float wb = (mbb & (1u << u)) ? __expf(eb - m1) : 0.f;             \
            den1 += wb;                                                       \
            AF1_.e[u] = (__bf16)wb;                                           \
        }                                                                     \
    }

#define K3_MFMA2(AF0_, AF1_, BP_)                                             \
    {                                                                         \
        _Pragma("unroll")                                                     \
        for (int nt = 0; nt < 16; ++nt) {                                     \
            bf16x8 bfr = *(const bf16x8*)((BP_) + nt * 1024);                 \
            acc0[nt] = __builtin_amdgcn_mfma_f32_16x16x32_bf16(               \
                AF0_.v, bfr, acc0[nt], 0, 0, 0);                              \
            acc1[nt] = __builtin_amdgcn_mfma_f32_16x16x32_bf16(               \
                AF1_.v, bfr, acc1[nt], 0, 0, 0);                              \
        }                                                                     \
    }

    for (int s = 0; s < STEPS; s += 2) {
        // ---- even: tile s in bh[0] ----
        union { bf16x8 v; __bf16 e[8]; } af0e, af1e;
        K3_WCOMP2(s, wpa.x, wpb.x, af0e, af1e);
        FENCE; VMCNT0; LGKM0; BARRIER;
        #pragma unroll
        for (int r = 0; r < 4; ++r)
            dma16(&hTs[ga[r] + (s + 1) * 32], &bh[1][cb[r] * 8]);
        if (s + 2 < STEPS) {
            wpan = *(const uint2*)&grow0[s + 2];
            wpbn = *(const uint2*)&grow1[s + 2];
        }
        FENCE;
        K3_MFMA2(af0e, af1e, bh0);
        // ---- odd: tile s+1 in bh[1] ----
        union { bf16x8 v; __bf16 e[8]; } af0o, af1o;
        K3_WCOMP2(s + 1, wpa.y, wpb.y, af0o, af1o);
        FENCE; VMCNT0; LGKM0; BARRIER;
        {
            int sn = (s + 2 < STEPS) ? s + 2 : 0;
            #pragma unroll
            for (int r = 0; r < 4; ++r)
                dma16(&hTs[ga[r] + sn * 32], &bh[0][cb[r] * 8]);
        }
        FENCE;
        K3_MFMA2(af0o, af1o, bh1);
        wpa = wpan;
        wpb = wpbn;
    }
    // epilogue: den = reduce over g lanes (xor bits 4,5)
    den0 += __shfl_xor(den0, 16);
    den0 += __shfl_xor(den0, 32);
    den1 += __shfl_xor(den1, 16);
    den1 += __shfl_xor(den1, 32);
    if (g == 0) {
        den[(size_t)seg * NN + row0] = den0;
        den[(size_t)seg * NN + row1] = den1;
    }
    // num: C layout col=ln, row m=g*4+rg within each 16-row tile
    #pragma unroll
    for (int nt = 0; nt < 16; ++nt)
        #pragma unroll
        for (int rg = 0; rg < 4; ++rg) {
            num[((size_t)seg * NN + i0 + wv * 32 + g * 4 + rg) * FF
                + nt * 16 + ln] = acc0[nt][rg];
            num[((size_t)seg * NN + i0 + wv * 32 + 16 + g * 4 + rg) * FF
                + nt * 16 + ln] = acc1[nt][rg];
        }
}

// ---------------- K4: out = relu( sum_s num / sum_s den ) -----------------
__global__ __launch_bounds__(256) void k4_out(const float* __restrict__ num,
                                              const float* __restrict__ den,
                                              float* __restrict__ out) {
    size_t f4 = (size_t)blockIdx.x * 256 + threadIdx.x;
    int i = (int)(f4 >> 6);
    int c4 = (int)(f4 & 63) << 2;
    float4 s = make_float4(0.f, 0.f, 0.f, 0.f);
    float d = 0.f;
    #pragma unroll
    for (int sg = 0; sg < SS; ++sg) {
        float4 v = *(const float4*)&num[((size_t)sg * NN + i) * FF + c4];
        s.x += v.x; s.y += v.y; s.z += v.z; s.w += v.w;
        d += den[(size_t)sg * NN + i];
    }
    float inv = 1.f / d;
    float4 o;
    o.x = fmaxf(s.x * inv, 0.f);
    o.y = fmaxf(s.y * inv, 0.f);
    o.z = fmaxf(s.z * inv, 0.f);
    o.w = fmaxf(s.w * inv, 0.f);
    *(float4*)&out[(size_t)i * FF + c4] = o;
}

extern "C" void kernel_launch(void* const* d_in, const int* in_sizes, int n_in,
                              void* d_out, int out_size, void* d_ws, size_t ws_size,
                              hipStream_t stream) {
    const float* X  = (const float*)d_in[0];
    const int*  adj = (const int*)d_in[1];
    const float* W  = (const float*)d_in[2];
    const float* a  = (const float*)d_in[3];
    float* out = (float*)d_out;
    char* ws = (char*)d_ws;

    const size_t off_hT   = 0;                                  // hi only: 4 MB
    const size_t off_wt   = off_hT + (size_t)FF * NN * 2;
    const size_t off_src  = off_wt + (size_t)2 * FF * FF * 2;
    const size_t off_dst  = off_src + (size_t)NN * 4;
    const size_t off_maxd = off_dst + (size_t)NN * 4;
    const size_t off_num  = off_maxd + 256;
    const size_t off_den  = off_num + (size_t)SS * NN * FF * 4;
    const size_t off_bits = off_den + (size_t)SS * NN * 4;

    __bf16* hT_ws = (__bf16*)(ws + off_hT);
    __bf16* wt_ws = (__bf16*)(ws + off_wt);
    float* src_ws = (float*)(ws + off_src);
    float* dst_ws = (float*)(ws + off_dst);
    unsigned* maxd = (unsigned*)(ws + off_maxd);
    float* num_ws = (float*)(ws + off_num);
    float* den_ws = (float*)(ws + off_den);
    unsigned* bits_ws = (unsigned*)(ws + off_bits);

    k02a<<<2064, 256, 0, stream>>>(W, wt_ws, adj, bits_ws, maxd);
    k1_h<<<NN / 32, 256, 0, stream>>>(X, wt_ws, a, hT_ws, src_ws, dst_ws, maxd);
    k3_attn<<<(NN / BI) * SS, 256, 0, stream>>>(bits_ws, hT_ws, src_ws, dst_ws, maxd,
                                                num_ws, den_ws);
    k4_out<<<(NN * FF / 4) / 256, 256, 0, stream>>>(num_ws, den_ws, out);
}

// Round 14
// 447.919 us; speedup vs baseline: 1.0235x; 1.0235x over previous
//
#include <hip/hip_runtime.h>
#include <math.h>

#define NN 8192
#define FF 256
#define ALPHA 0.2f
#define SS 8                 // j-segments
#define JSEG (NN / SS)       // 1024
#define STEPS (JSEG / 32)    // 32 steps of 32 j each
#define BI 128               // i-rows per k3 block (8 waves x 16 rows)

typedef __bf16 bf16x8 __attribute__((ext_vector_type(8)));
typedef __bf16 bf16x4 __attribute__((ext_vector_type(4)));
typedef float  f32x4  __attribute__((ext_vector_type(4)));

__device__ __forceinline__ void dma16(const void* g, void* l) {
    __builtin_amdgcn_global_load_lds((const __attribute__((address_space(1))) void*)g,
                                     (__attribute__((address_space(3))) void*)l,
                                     16, 0, 0);
}

#define VMCNT2   asm volatile("s_waitcnt vmcnt(2)" ::: "memory")
#define LGKM0    asm volatile("s_waitcnt lgkmcnt(0)" ::: "memory")
#define BARRIER  asm volatile("s_barrier" ::: "memory")
#define FENCE    asm volatile("" ::: "memory")

// ---------------- K0: WT[hl][n][k] bf16 hi/lo from W[k][n] fp32 -----------
__global__ __launch_bounds__(256) void k0_wt(const float* __restrict__ W,
                                             __bf16* __restrict__ WT) {
    __shared__ float ts[64][65];
    const int t = threadIdx.x;
    const int k0 = blockIdx.x * 64;
    const int n0 = blockIdx.y * 64;
    #pragma unroll
    for (int r = 0; r < 4; ++r) {
        int krow = r * 16 + (t >> 4);
        int nc4 = (t & 15) * 4;
        *(float4*)&ts[krow][nc4] = *(const float4*)&W[(size_t)(k0 + krow) * FF + n0 + nc4];
    }
    __syncthreads();
    const int nloc = t >> 2;
    const int kc = (t & 3) * 16;
    union { bf16x8 v[2]; __bf16 e[16]; } hi, lo;
    #pragma unroll
    for (int u = 0; u < 16; ++u) {
        float x = ts[kc + u][nloc];
        __bf16 h1 = (__bf16)x;
        hi.e[u] = h1;
        lo.e[u] = (__bf16)(x - (float)h1);
    }
    size_t base = (size_t)(n0 + nloc) * FF + k0 + kc;
    *(bf16x8*)&WT[base] = hi.v[0];
    *(bf16x8*)&WT[base + 8] = hi.v[1];
    size_t lbase = (size_t)FF * FF + base;
    *(bf16x8*)&WT[lbase] = lo.v[0];
    *(bf16x8*)&WT[lbase + 8] = lo.v[1];
}

// ---------------- K1: MFMA h-tile -> hT(seg-major) + src/dst + maxd -------
__global__ __launch_bounds__(256) void k1_h(const float* __restrict__ X,
                                            const __bf16* __restrict__ WT,
                                            const float* __restrict__ a,
                                            __bf16* __restrict__ hT,
                                            float* __restrict__ src,
                                            float* __restrict__ dst,
                                            unsigned* __restrict__ maxd) {
    __shared__ __bf16 ax[2][32][40];
    __shared__ float hs[32][264];
    __shared__ float red[2][4][32];
    const int t = threadIdx.x;
    const int i0 = blockIdx.x * 32;
    const int l = t & 63, wv = t >> 6, ln = l & 15, g = l >> 4;
    f32x4 acc[2][4];
    #pragma unroll
    for (int mt = 0; mt < 2; ++mt)
        #pragma unroll
        for (int nt = 0; nt < 4; ++nt)
            acc[mt][nt] = (f32x4){0.f, 0.f, 0.f, 0.f};

    for (int ks = 0; ks < 8; ++ks) {
        const int k0 = ks * 32;
        {
            int row = t >> 3, c4 = (t & 7) * 4;
            float4 xv = *(const float4*)&X[(size_t)(i0 + row) * FF + k0 + c4];
            bf16x4 hi4, lo4;
            float xs_[4] = {xv.x, xv.y, xv.z, xv.w};
            #pragma unroll
            for (int u = 0; u < 4; ++u) {
                __bf16 h1 = (__bf16)xs_[u];
                hi4[u] = h1;
                lo4[u] = (__bf16)(xs_[u] - (float)h1);
            }
            *(bf16x4*)&ax[0][row][c4] = hi4;
            *(bf16x4*)&ax[1][row][c4] = lo4;
        }
        __syncthreads();
        bf16x8 ah[2], al[2];
        ah[0] = *(bf16x8*)&ax[0][ln][g * 8];
        ah[1] = *(bf16x8*)&ax[0][16 + ln][g * 8];
        al[0] = *(bf16x8*)&ax[1][ln][g * 8];
        al[1] = *(bf16x8*)&ax[1][16 + ln][g * 8];
        #pragma unroll
        for (int nt = 0; nt < 4; ++nt) {
            const int n = wv * 64 + nt * 16 + ln;
            bf16x8 bh8 = *(const bf16x8*)&WT[(size_t)n * FF + k0 + g * 8];
            bf16x8 bl8 = *(const bf16x8*)&WT[(size_t)(FF + n) * FF + k0 + g * 8];
            #pragma unroll
            for (int mt = 0; mt < 2; ++mt) {
                acc[mt][nt] = __builtin_amdgcn_mfma_f32_16x16x32_bf16(ah[mt], bh8, acc[mt][nt], 0, 0, 0);
                acc[mt][nt] = __builtin_amdgcn_mfma_f32_16x16x32_bf16(ah[mt], bl8, acc[mt][nt], 0, 0, 0);
                acc[mt][nt] = __builtin_amdgcn_mfma_f32_16x16x32_bf16(al[mt], bh8, acc[mt][nt], 0, 0, 0);
            }
        }
        __syncthreads();
    }
    float an[4], ad[4];
    #pragma unroll
    for (int nt = 0; nt < 4; ++nt) {
        an[nt] = a[wv * 64 + nt * 16 + ln];
        ad[nt] = a[FF + wv * 64 + nt * 16 + ln];
    }
    float sp[2][4], dp[2][4];
    #pragma unroll
    for (int mt = 0; mt < 2; ++mt)
        #pragma unroll
        for (int rg = 0; rg < 4; ++rg) { sp[mt][rg] = 0.f; dp[mt][rg] = 0.f; }
    #pragma unroll
    for (int mt = 0; mt < 2; ++mt)
        #pragma unroll
        for (int nt = 0; nt < 4; ++nt)
            #pragma unroll
            for (int rg = 0; rg < 4; ++rg) {
                float v = acc[mt][nt][rg];
                hs[mt * 16 + g * 4 + rg][wv * 64 + nt * 16 + ln] = v;
                sp[mt][rg] += v * an[nt];
                dp[mt][rg] += v * ad[nt];
            }
    #pragma unroll
    for (int mk = 1; mk < 16; mk <<= 1)
        #pragma unroll
        for (int mt = 0; mt < 2; ++mt)
            #pragma unroll
            for (int rg = 0; rg < 4; ++rg) {
                sp[mt][rg] += __shfl_xor(sp[mt][rg], mk);
                dp[mt][rg] += __shfl_xor(dp[mt][rg], mk);
            }
    if (ln == 0) {
        #pragma unroll
        for (int mt = 0; mt < 2; ++mt)
            #pragma unroll
            for (int rg = 0; rg < 4; ++rg) {
                red[0][wv][mt * 16 + g * 4 + rg] = sp[mt][rg];
                red[1][wv][mt * 16 + g * 4 + rg] = dp[mt][rg];
            }
    }
    __syncthreads();
    if (t < 32) {
        src[i0 + t] = red[0][0][t] + red[0][1][t] + red[0][2][t] + red[0][3][t];
        float dv_ = red[1][0][t] + red[1][1][t] + red[1][2][t] + red[1][3][t];
        dst[i0 + t] = dv_;
        unsigned u = __float_as_uint(dv_);
        unsigned key = (u & 0x80000000u) ? ~u : (u | 0x80000000u);
        atomicMax(maxd, key);
    }
    {
        const int f = t;
        const int seg_i = i0 >> 10;             // i0 / JSEG
        const int ilb = i0 & (JSEG - 1);
        #pragma unroll
        for (int jc = 0; jc < 4; ++jc) {
            union { bf16x8 v; __bf16 e[8]; } hi;
            #pragma unroll
            for (int u = 0; u < 8; ++u) {
                float x = hs[jc * 8 + u][f];
                hi.e[u] = (__bf16)x;
            }
            *(bf16x8*)&hT[((size_t)seg_i * FF + f) * JSEG + ilb + jc * 8] = hi.v;
        }
    }
}

// ---------------- K2a: pack adj int32 -> 1 bit/elem; init maxd ------------
__global__ __launch_bounds__(256) void k2a_pack(const int* __restrict__ adj,
                                                unsigned* __restrict__ bits,
                                                unsigned* __restrict__ maxd) {
    if (blockIdx.x == 0 && threadIdx.x == 0) maxd[0] = 0u;  // key of -inf
    const size_t total4 = (size_t)NN * NN / 4;
    const int l = threadIdx.x & 63;
    const int base = l & 56;
    size_t t = (size_t)blockIdx.x * 256 + threadIdx.x;
    const size_t stride = (size_t)gridDim.x * 256;
    for (; t < total4; t += stride) {
        int4 v = ((const int4*)adj)[t];
        unsigned nib = (unsigned)(v.x > 0) | ((unsigned)(v.y > 0) << 1)
                     | ((unsigned)(v.z > 0) << 2) | ((unsigned)(v.w > 0) << 3);
        unsigned w = 0;
        #pragma unroll
        for (int k = 0; k < 8; ++k)
            w |= (unsigned)__shfl((int)nib, base + k) << (4 * k);
        if ((l & 7) == 0)
            bits[t >> 3] = w;
    }
}

// ---------------- K3: depth-2 counted-vmcnt MFMA attention ----------------
// Exactly the R11/446us-verified structure with ONE change: 3-buffer B-tile
// pipeline with vmcnt(2) (T3/T4) instead of vmcnt(0) depth-1 drain. The
// in-loop mask register prefetch (a vmem load that would pollute the hand
// vmcnt count) moves to a prologue-staged LDS tile (stride 33 words:
// conflict-free broadcast reads). Per step: vmcnt(2) retires only tile s
// (FIFO; tile s+1's 2 loads stay in flight); barrier; issue DMA(s+2) ->
// each DMA gets ~2 full steps of latency cover instead of ~300 cyc.
// Hazards: RAW tile s via vmcnt(2)+barrier (FIFO retire order); WAR on
// buf[(s+2)%3] (its readers ran at step s-1, drained by LGKM0+barrier(s)).
__global__ __launch_bounds__(512, 4) void k3_attn(const unsigned* __restrict__ bits,
                                                  const __bf16* __restrict__ hT,
                                                  const float* __restrict__ src,
                                                  const float* __restrict__ dst,
                                                  const unsigned* __restrict__ maxd,
                                                  float* __restrict__ num,
                                                  float* __restrict__ den) {
    __shared__ __bf16 bh[3][1024 * 8];      // 48 KB B-tile triple buffer
    __shared__ unsigned mlds[BI * 33];      // 16.9 KB mask tile (stride 33)
    __shared__ float dsts[JSEG];            // 4 KB dst segment
    const int t = threadIdx.x;
    const int l = t & 63, wv = t >> 6, ln = l & 15, g = l >> 4;
    const int seg = blockIdx.x & 7;         // seg -> XCD affinity
    const int it = blockIdx.x >> 3;         // NN/BI = 64 i-tiles
    const int i0 = it * BI;
    const int jbeg = seg * JSEG;
    const int rl = wv * 16 + ln;
    const int row = i0 + rl;
    const unsigned mk_ = maxd[0];
    const float maxdv = (mk_ & 0x80000000u) ? __uint_as_float(mk_ & 0x7fffffffu)
                                            : __uint_as_float(~mk_);
    const float src_r = src[row];
    const float e0 = src_r + maxdv;
    const float m_r = e0 > 0.f ? e0 : ALPHA * e0;   // per-row shift >= row max

    // segment-local B panel (contiguous 512 KB)
    const __bf16* hTs = hT + (size_t)seg * FF * JSEG;

    // DMA descriptors: 2 chunks/thread (1024 chunks), lane-linear LDS,
    // swizzle on gaddr. Chunk c = f*4+pc holds hTs[f][jl+(pc^((f>>1)&3))*8..+8]
    // at byte c*16.
    int ga[2], cb[2];
    #pragma unroll
    for (int r = 0; r < 2; ++r) {
        int cbase = r * 512 + wv * 64;
        int c = cbase + l;
        int f = c >> 2;
        int pc = c & 3;
        int jc = pc ^ ((f >> 1) & 3);
        ga[r] = f * JSEG + jc * 8;      // seg-local offset
        cb[r] = __builtin_amdgcn_readfirstlane(cbase);
    }
    // B-read base (BYTES): f=nt*16+ln -> elem off = f*32 + (g^sw)*8
    const int rb = ln * 64 + ((g ^ ((ln >> 1) & 3)) * 16);

    // ---- prologue: DMA tile 0; mask tile + dst segment -> LDS ----
    #pragma unroll
    for (int r = 0; r < 2; ++r)
        dma16(&hTs[ga[r]], &bh[0][cb[r] * 8]);
    FENCE;
    {
        int r = t >> 2;                 // 0..127
        int c = (t & 3) * 8;            // word offset
        const unsigned* gsrc = bits + (size_t)(i0 + r) * (NN / 32) + (jbeg >> 5) + c;
        uint4 w0 = *(const uint4*)gsrc;
        uint4 w1 = *(const uint4*)(gsrc + 4);
        unsigned* ldst = &mlds[r * 33 + c];
        ldst[0] = w0.x; ldst[1] = w0.y; ldst[2] = w0.z; ldst[3] = w0.w;
        ldst[4] = w1.x; ldst[5] = w1.y; ldst[6] = w1.z; ldst[7] = w1.w;
    }
    if (t < 256) *(float4*)&dsts[t * 4] = *(const float4*)&dst[jbeg + t * 4];
    __syncthreads();            // drains vmcnt(0)+lgkmcnt(0): tile 0 + LDS ready

    // issue DMA tile 1 -> bh[1]; the only outstanding vmem at loop entry
    #pragma unroll
    for (int r = 0; r < 2; ++r)
        dma16(&hTs[ga[r] + 32], &bh[1][cb[r] * 8]);
    FENCE;

    float den_reg = 0.f;
    f32x4 acc[16];
    #pragma unroll
    for (int nt = 0; nt < 16; ++nt) acc[nt] = (f32x4){0.f, 0.f, 0.f, 0.f};

    int cur = 0;                              // buffer holding tile s
    for (int s = 0; s < STEPS; ++s) {
        // ---- WCOMP from LDS: mask word (stride-33, broadcast) + dst slice ----
        unsigned mb = (mlds[rl * 33 + s] >> (g * 8)) & 0xffu;
        const float* dp_ = &dsts[s * 32 + g * 8];
        float4 dq0 = *(const float4*)dp_;
        float4 dq1 = *(const float4*)(dp_ + 4);
        const float dv[8] = {dq0.x, dq0.y, dq0.z, dq0.w,
                             dq1.x, dq1.y, dq1.z, dq1.w};
        union { bf16x8 v; __bf16 e[8]; } af;
        #pragma unroll
        for (int u = 0; u < 8; ++u) {
            float e = src_r + dv[u];
            e = e > 0.f ? e : ALPHA * e;
            float ex = __expf(e - m_r);
            float w = (mb & (1u << u)) ? ex : 0.f;
            den_reg += w;
            af.e[u] = (__bf16)w;
        }
        // ---- counted drain: retire tile s only; tile s+1 stays in flight ----
        FENCE; VMCNT2; LGKM0; BARRIER;
        // ---- issue DMA tile s+2 into buf[(cur+2)%3] (read last at s-1) ----
        {
            int sn = s + 2;
            if (sn >= STEPS) sn -= STEPS;
            int db = cur + 2;
            if (db >= 3) db -= 3;
            #pragma unroll
            for (int r = 0; r < 2; ++r)
                dma16(&hTs[ga[r] + sn * 32], &bh[db][cb[r] * 8]);
        }
        FENCE;
        // ---- MFMA on tile s ----
        const char* bp = (const char*)&bh[0][0] + cur * 16384 + rb;
        #pragma unroll
        for (int nt = 0; nt < 16; ++nt) {
            bf16x8 bfr = *(const bf16x8*)(bp + nt * 1024);
            acc[nt] = __builtin_amdgcn_mfma_f32_16x16x32_bf16(af.v, bfr, acc[nt], 0, 0, 0);
        }
        if (++cur == 3) cur = 0;
    }
    // epilogue: den = reduce over g lanes (xor bits 4,5)
    den_reg += __shfl_xor(den_reg, 16);
    den_reg += __shfl_xor(den_reg, 32);
    if (g == 0) den[(size_t)seg * NN + row] = den_reg;
    // num: C layout col=ln, row m=g*4+rg within wave's 16-row tile
    #pragma unroll
    for (int nt = 0; nt < 16; ++nt)
        #pragma unroll
        for (int rg = 0; rg < 4; ++rg)
            num[((size_t)seg * NN + i0 + wv * 16 + g * 4 + rg) * FF
                + nt * 16 + ln] = acc[nt][rg];
}

// ---------------- K4: out = relu( sum_s num / sum_s den ) -----------------
__global__ __launch_bounds__(256) void k4_out(const float* __restrict__ num,
                                              const float* __restrict__ den,
                                              float* __restrict__ out) {
    size_t f4 = (size_t)blockIdx.x * 256 + threadIdx.x;
    int i = (int)(f4 >> 6);
    int c4 = (int)(f4 & 63) << 2;
    float4 s = make_float4(0.f, 0.f, 0.f, 0.f);
    float d = 0.f;
    #pragma unroll
    for (int sg = 0; sg < SS; ++sg) {
        float4 v = *(const float4*)&num[((size_t)sg * NN + i) * FF + c4];
        s.x += v.x; s.y += v.y; s.z += v.z; s.w += v.w;
        d += den[(size_t)sg * NN + i];
    }
    float inv = 1.f / d;
    float4 o;
    o.x = fmaxf(s.x * inv, 0.f);
    o.y = fmaxf(s.y * inv, 0.f);
    o.z = fmaxf(s.z * inv, 0.f);
    o.w = fmaxf(s.w * inv, 0.f);
    *(float4*)&out[(size_t)i * FF + c4] = o;
}

extern "C" void kernel_launch(void* const* d_in, const int* in_sizes, int n_in,
                              void* d_out, int out_size, void* d_ws, size_t ws_size,
                              hipStream_t stream) {
    const float* X  = (const float*)d_in[0];
    const int*  adj = (const int*)d_in[1];
    const float* W  = (const float*)d_in[2];
    const float* a  = (const float*)d_in[3];
    float* out = (float*)d_out;
    char* ws = (char*)d_ws;

    const size_t off_hT   = 0;                                  // hi only: 4 MB
    const size_t off_wt   = off_hT + (size_t)FF * NN * 2;
    const size_t off_src  = off_wt + (size_t)2 * FF * FF * 2;
    const size_t off_dst  = off_src + (size_t)NN * 4;
    const size_t off_maxd = off_dst + (size_t)NN * 4;
    const size_t off_num  = off_maxd + 256;
    const size_t off_den  = off_num + (size_t)SS * NN * FF * 4;
    const size_t off_bits = off_den + (size_t)SS * NN * 4;

    __bf16* hT_ws = (__bf16*)(ws + off_hT);
    __bf16* wt_ws = (__bf16*)(ws + off_wt);
    float* src_ws = (float*)(ws + off_src);
    float* dst_ws = (float*)(ws + off_dst);
    unsigned* maxd = (unsigned*)(ws + off_maxd);
    float* num_ws = (float*)(ws + off_num);
    float* den_ws = (float*)(ws + off_den);
    unsigned* bits_ws = (unsigned*)(ws + off_bits);

    k2a_pack<<<2048, 256, 0, stream>>>(adj, bits_ws, maxd);
    k0_wt<<<dim3(FF / 64, FF / 64), 256, 0, stream>>>(W, wt_ws);
    k1_h<<<NN / 32, 256, 0, stream>>>(X, wt_ws, a, hT_ws, src_ws, dst_ws, maxd);
    k3_attn<<<(NN / BI) * SS, 512, 0, stream>>>(bits_ws, hT_ws, src_ws, dst_ws, maxd,
                                                num_ws, den_ws);
    k4_out<<<(NN * FF / 4) / 256, 256, 0, stream>>>(num_ws, den_ws, out);
}

// Round 15
// 443.325 us; speedup vs baseline: 1.0342x; 1.0104x over previous
//
#include <hip/hip_runtime.h>
#include <math.h>

#define NN 8192
#define FF 256
#define ALPHA 0.2f
#define L2E 1.4426950408889634f   // log2(e): pre-scale so exp(x) == exp2(x*L2E)
#define SS 8                 // j-segments
#define JSEG (NN / SS)       // 1024
#define STEPS (JSEG / 32)    // 32 steps of 32 j each (even)
#define BI 128               // i-rows per k3 block (8 waves x 16 rows)

typedef __bf16 bf16x8 __attribute__((ext_vector_type(8)));
typedef __bf16 bf16x4 __attribute__((ext_vector_type(4)));
typedef float  f32x4  __attribute__((ext_vector_type(4)));

__device__ __forceinline__ void dma16(const void* g, void* l) {
    __builtin_amdgcn_global_load_lds((const __attribute__((address_space(1))) void*)g,
                                     (__attribute__((address_space(3))) void*)l,
                                     16, 0, 0);
}

#define VMCNT0   asm volatile("s_waitcnt vmcnt(0)" ::: "memory")
#define LGKM0    asm volatile("s_waitcnt lgkmcnt(0)" ::: "memory")
#define BARRIER  asm volatile("s_barrier" ::: "memory")
#define FENCE    asm volatile("" ::: "memory")

// ---------------- K02a: fused W->WT convert (blocks 0..15) + adj pack -----
// Independent work, block-range split (verified passing in R12): -1 launch.
__global__ __launch_bounds__(256) void k02a(const float* __restrict__ W,
                                            __bf16* __restrict__ WT,
                                            const int* __restrict__ adj,
                                            unsigned* __restrict__ bits,
                                            unsigned* __restrict__ maxd) {
    __shared__ float ts[64][65];
    const int t = threadIdx.x;
    if (blockIdx.x < 16) {
        // ---- k0 body: WT[hl][n][k] bf16 hi/lo from W[k][n] fp32 ----
        const int k0 = (blockIdx.x & 3) * 64;
        const int n0 = (blockIdx.x >> 2) * 64;
        #pragma unroll
        for (int r = 0; r < 4; ++r) {
            int krow = r * 16 + (t >> 4);
            int nc4 = (t & 15) * 4;
            *(float4*)&ts[krow][nc4] = *(const float4*)&W[(size_t)(k0 + krow) * FF + n0 + nc4];
        }
        __syncthreads();
        const int nloc = t >> 2;
        const int kc = (t & 3) * 16;
        union { bf16x8 v[2]; __bf16 e[16]; } hi, lo;
        #pragma unroll
        for (int u = 0; u < 16; ++u) {
            float x = ts[kc + u][nloc];
            __bf16 h1 = (__bf16)x;
            hi.e[u] = h1;
            lo.e[u] = (__bf16)(x - (float)h1);
        }
        size_t base = (size_t)(n0 + nloc) * FF + k0 + kc;
        *(bf16x8*)&WT[base] = hi.v[0];
        *(bf16x8*)&WT[base + 8] = hi.v[1];
        size_t lbase = (size_t)FF * FF + base;
        *(bf16x8*)&WT[lbase] = lo.v[0];
        *(bf16x8*)&WT[lbase + 8] = lo.v[1];
        return;
    }
    // ---- k2a body: pack adj int32 -> 1 bit/elem; init maxd ----
    if (blockIdx.x == 16 && t == 0) maxd[0] = 0u;   // key of -inf
    const size_t total4 = (size_t)NN * NN / 4;
    const int l = t & 63;
    const int base = l & 56;
    size_t p = (size_t)(blockIdx.x - 16) * 256 + t;
    const size_t stride = (size_t)(gridDim.x - 16) * 256;
    for (; p < total4; p += stride) {
        int4 v = ((const int4*)adj)[p];
        unsigned nib = (unsigned)(v.x > 0) | ((unsigned)(v.y > 0) << 1)
                     | ((unsigned)(v.z > 0) << 2) | ((unsigned)(v.w > 0) << 3);
        unsigned w = 0;
        #pragma unroll
        for (int k = 0; k < 8; ++k)
            w |= (unsigned)__shfl((int)nib, base + k) << (4 * k);
        if ((l & 7) == 0)
            bits[p >> 3] = w;
    }
}

// ---------------- K1: MFMA h-tile -> hT(seg-major) + src/dst + maxd -------
// src/dst stored PRE-SCALED by log2(e) (LeakyReLU is positively homogeneous:
// leaky(L2E*x) = L2E*leaky(x); max commutes with positive scale) so k3's
// exp becomes a bare v_exp_f32 (exp2) with no per-element mul.
__global__ __launch_bounds__(256) void k1_h(const float* __restrict__ X,
                                            const __bf16* __restrict__ WT,
                                            const float* __restrict__ a,
                                            __bf16* __restrict__ hT,
                                            float* __restrict__ src,
                                            float* __restrict__ dst,
                                            unsigned* __restrict__ maxd) {
    __shared__ __bf16 ax[2][32][40];
    __shared__ float hs[32][264];
    __shared__ float red[2][4][32];
    const int t = threadIdx.x;
    const int i0 = blockIdx.x * 32;
    const int l = t & 63, wv = t >> 6, ln = l & 15, g = l >> 4;
    f32x4 acc[2][4];
    #pragma unroll
    for (int mt = 0; mt < 2; ++mt)
        #pragma unroll
        for (int nt = 0; nt < 4; ++nt)
            acc[mt][nt] = (f32x4){0.f, 0.f, 0.f, 0.f};

    for (int ks = 0; ks < 8; ++ks) {
        const int k0 = ks * 32;
        {
            int row = t >> 3, c4 = (t & 7) * 4;
            float4 xv = *(const float4*)&X[(size_t)(i0 + row) * FF + k0 + c4];
            bf16x4 hi4, lo4;
            float xs_[4] = {xv.x, xv.y, xv.z, xv.w};
            #pragma unroll
            for (int u = 0; u < 4; ++u) {
                __bf16 h1 = (__bf16)xs_[u];
                hi4[u] = h1;
                lo4[u] = (__bf16)(xs_[u] - (float)h1);
            }
            *(bf16x4*)&ax[0][row][c4] = hi4;
            *(bf16x4*)&ax[1][row][c4] = lo4;
        }
        __syncthreads();
        bf16x8 ah[2], al[2];
        ah[0] = *(bf16x8*)&ax[0][ln][g * 8];
        ah[1] = *(bf16x8*)&ax[0][16 + ln][g * 8];
        al[0] = *(bf16x8*)&ax[1][ln][g * 8];
        al[1] = *(bf16x8*)&ax[1][16 + ln][g * 8];
        #pragma unroll
        for (int nt = 0; nt < 4; ++nt) {
            const int n = wv * 64 + nt * 16 + ln;
            bf16x8 bh8 = *(const bf16x8*)&WT[(size_t)n * FF + k0 + g * 8];
            bf16x8 bl8 = *(const bf16x8*)&WT[(size_t)(FF + n) * FF + k0 + g * 8];
            #pragma unroll
            for (int mt = 0; mt < 2; ++mt) {
                acc[mt][nt] = __builtin_amdgcn_mfma_f32_16x16x32_bf16(ah[mt], bh8, acc[mt][nt], 0, 0, 0);
                acc[mt][nt] = __builtin_amdgcn_mfma_f32_16x16x32_bf16(ah[mt], bl8, acc[mt][nt], 0, 0, 0);
                acc[mt][nt] = __builtin_amdgcn_mfma_f32_16x16x32_bf16(al[mt], bh8, acc[mt][nt], 0, 0, 0);
            }
        }
        __syncthreads();
    }
    float an[4], ad[4];
    #pragma unroll
    for (int nt = 0; nt < 4; ++nt) {
        an[nt] = a[wv * 64 + nt * 16 + ln];
        ad[nt] = a[FF + wv * 64 + nt * 16 + ln];
    }
    float sp[2][4], dp[2][4];
    #pragma unroll
    for (int mt = 0; mt < 2; ++mt)
        #pragma unroll
        for (int rg = 0; rg < 4; ++rg) { sp[mt][rg] = 0.f; dp[mt][rg] = 0.f; }
    #pragma unroll
    for (int mt = 0; mt < 2; ++mt)
        #pragma unroll
        for (int nt = 0; nt < 4; ++nt)
            #pragma unroll
            for (int rg = 0; rg < 4; ++rg) {
                float v = acc[mt][nt][rg];
                hs[mt * 16 + g * 4 + rg][wv * 64 + nt * 16 + ln] = v;
                sp[mt][rg] += v * an[nt];
                dp[mt][rg] += v * ad[nt];
            }
    #pragma unroll
    for (int mk = 1; mk < 16; mk <<= 1)
        #pragma unroll
        for (int mt = 0; mt < 2; ++mt)
            #pragma unroll
            for (int rg = 0; rg < 4; ++rg) {
                sp[mt][rg] += __shfl_xor(sp[mt][rg], mk);
                dp[mt][rg] += __shfl_xor(dp[mt][rg], mk);
            }
    if (ln == 0) {
        #pragma unroll
        for (int mt = 0; mt < 2; ++mt)
            #pragma unroll
            for (int rg = 0; rg < 4; ++rg) {
                red[0][wv][mt * 16 + g * 4 + rg] = sp[mt][rg];
                red[1][wv][mt * 16 + g * 4 + rg] = dp[mt][rg];
            }
    }
    __syncthreads();
    if (t < 32) {
        src[i0 + t] = (red[0][0][t] + red[0][1][t] + red[0][2][t] + red[0][3][t]) * L2E;
        float dv_ = (red[1][0][t] + red[1][1][t] + red[1][2][t] + red[1][3][t]) * L2E;
        dst[i0 + t] = dv_;
        unsigned u = __float_as_uint(dv_);
        unsigned key = (u & 0x80000000u) ? ~u : (u | 0x80000000u);
        atomicMax(maxd, key);
    }
    {
        const int f = t;
        const int seg_i = i0 >> 10;             // i0 / JSEG
        const int ilb = i0 & (JSEG - 1);
        #pragma unroll
        for (int jc = 0; jc < 4; ++jc) {
            union { bf16x8 v; __bf16 e[8]; } hi;
            #pragma unroll
            for (int u = 0; u < 8; ++u) {
                float x = hs[jc * 8 + u][f];
                hi.e[u] = (__bf16)x;
            }
            *(bf16x8*)&hT[((size_t)seg_i * FF + f) * JSEG + ilb + jc * 8] = hi.v;
        }
    }
}

// ---------------- K3: R11 (446us-verified) + thinned WCOMP ----------------
// Structure identical to the tied-best R11 config (BI=128, 8 waves, depth-1
// DMA, vmcnt0+lgkm0+barrier, seg-major hTs, in-loop uint2 mask prefetch).
// WCOMP thinning: scaled domain -> bare v_exp_f32 (no per-elem mul);
// leaky via fmaxf(e, 0.2e) (exact for alpha>0).
__global__ __launch_bounds__(512, 4) void k3_attn(const unsigned* __restrict__ bits,
                                                  const __bf16* __restrict__ hT,
                                                  const float* __restrict__ src,
                                                  const float* __restrict__ dst,
                                                  const unsigned* __restrict__ maxd,
                                                  float* __restrict__ num,
                                                  float* __restrict__ den) {
    __shared__ __bf16 bh[2][1024 * 8];      // 32 KB B-tile double buffer
    __shared__ float dsts[JSEG];            // 4 KB dst segment
    const int t = threadIdx.x;
    const int l = t & 63, wv = t >> 6, ln = l & 15, g = l >> 4;
    const int seg = blockIdx.x & 7;         // seg -> XCD affinity
    const int it = blockIdx.x >> 3;         // NN/BI = 64 i-tiles
    const int i0 = it * BI;
    const int jbeg = seg * JSEG;
    const int row = i0 + wv * 16 + ln;
    const unsigned mk_ = maxd[0];
    const float maxdv = (mk_ & 0x80000000u) ? __uint_as_float(mk_ & 0x7fffffffu)
                                            : __uint_as_float(~mk_);
    const float src_r = src[row];           // scaled domain
    const float e0 = src_r + maxdv;
    const float m_r = fmaxf(e0, ALPHA * e0); // per-row shift >= row max (scaled)

    // segment-local B panel (contiguous 512 KB)
    const __bf16* hTs = hT + (size_t)seg * FF * JSEG;

    // DMA descriptors: 2 chunks/thread (1024 chunks), lane-linear LDS,
    // swizzle on gaddr. Chunk c = f*4+pc holds hTs[f][jl+(pc^((f>>1)&3))*8..+8]
    // at byte c*16.
    int ga[2], cb[2];
    #pragma unroll
    for (int r = 0; r < 2; ++r) {
        int cbase = r * 512 + wv * 64;
        int c = cbase + l;
        int f = c >> 2;
        int pc = c & 3;
        int jc = pc ^ ((f >> 1) & 3);
        ga[r] = f * JSEG + jc * 8;      // seg-local offset
        cb[r] = __builtin_amdgcn_readfirstlane(cbase);
    }
    // B-read base (BYTES): f=nt*16+ln -> elem off = f*32 + (g^sw)*8
    const int rb = ln * 64 + ((g ^ ((ln >> 1) & 3)) * 16);
    const char* bh0 = (const char*)&bh[0][0] + rb;
    const char* bh1 = (const char*)&bh[1][0] + rb;

    // mask source: word s of this row's segment
    const unsigned* grow = bits + (size_t)row * (NN / 32) + (jbeg >> 5);

    // prologue: DMA tile 0 -> bh[0]; dst segment -> LDS; mask pair 0 -> regs
    #pragma unroll
    for (int r = 0; r < 2; ++r)
        dma16(&hTs[ga[r]], &bh[0][cb[r] * 8]);
    FENCE;
    if (t < 256) *(float4*)&dsts[t * 4] = *(const float4*)&dst[jbeg + t * 4];
    uint2 wp = *(const uint2*)&grow[0];
    uint2 wpn = wp;
    __syncthreads();            // drains vmcnt(0)+lgkmcnt(0): tile 0 + dsts ready

    float den_reg = 0.f;
    f32x4 acc[16];
    #pragma unroll
    for (int nt = 0; nt < 16; ++nt) acc[nt] = (f32x4){0.f, 0.f, 0.f, 0.f};

#define K3_WCOMP(S_, MW_, AF_)                                                \
    {                                                                         \
        unsigned mb = ((MW_) >> (g * 8)) & 0xffu;                             \
        const float* dp_ = &dsts[(S_) * 32 + g * 8];                          \
        float4 dq0 = *(const float4*)dp_;                                     \
        float4 dq1 = *(const float4*)(dp_ + 4);                               \
        const float dv[8] = {dq0.x, dq0.y, dq0.z, dq0.w,                      \
                             dq1.x, dq1.y, dq1.z, dq1.w};                     \
        _Pragma("unroll")                                                     \
        for (int u = 0; u < 8; ++u) {                                         \
            float e = src_r + dv[u];                                          \
            e = fmaxf(e, ALPHA * e);            /* leaky, scaled domain */    \
            float ex;                                                         \
            asm("v_exp_f32 %0, %1" : "=v"(ex) : "v"(e - m_r)); /* exp2 */     \
            float w = (mb & (1u << u)) ? ex : 0.f;                            \
            den_reg += w;                                                     \
            AF_.e[u] = (__bf16)w;                                             \
        }                                                                     \
    }

#define K3_MFMA(AF_, BP_)                                                     \
    {                                                                         \
        _Pragma("unroll")                                                     \
        for (int nt = 0; nt < 16; ++nt) {                                     \
            bf16x8 bfr = *(const bf16x8*)((BP_) + nt * 1024);                 \
            acc[nt] = __builtin_amdgcn_mfma_f32_16x16x32_bf16(                \
                AF_.v, bfr, acc[nt], 0, 0, 0);                                \
        }                                                                     \
    }

    for (int s = 0; s < STEPS; s += 2) {
        // ---- even: tile s in bh[0] ----
        union { bf16x8 v; __bf16 e[8]; } afe;
        K3_WCOMP(s, wp.x, afe);
        FENCE; VMCNT0; LGKM0; BARRIER;
        #pragma unroll
        for (int r = 0; r < 2; ++r)
            dma16(&hTs[ga[r] + (s + 1) * 32], &bh[1][cb[r] * 8]);
        if (s + 2 < STEPS) wpn = *(const uint2*)&grow[s + 2];
        FENCE;
        K3_MFMA(afe, bh0);
        // ---- odd: tile s+1 in bh[1] ----
        union { bf16x8 v; __bf16 e[8]; } afo;
        K3_WCOMP(s + 1, wp.y, afo);
        FENCE; VMCNT0; LGKM0; BARRIER;
        {
            int sn = (s + 2 < STEPS) ? s + 2 : 0;
            #pragma unroll
            for (int r = 0; r < 2; ++r)
                dma16(&hTs[ga[r] + sn * 32], &bh[0][cb[r] * 8]);
        }
        FENCE;
        K3_MFMA(afo, bh1);
        wp = wpn;
    }
    // epilogue: den = reduce over g lanes (xor bits 4,5)
    den_reg += __shfl_xor(den_reg, 16);
    den_reg += __shfl_xor(den_reg, 32);
    if (g == 0) den[(size_t)seg * NN + row] = den_reg;
    // num: C layout col=ln, row m=g*4+rg within wave's 16-row tile
    #pragma unroll
    for (int nt = 0; nt < 16; ++nt)
        #pragma unroll
        for (int rg = 0; rg < 4; ++rg)
            num[((size_t)seg * NN + i0 + wv * 16 + g * 4 + rg) * FF
                + nt * 16 + ln] = acc[nt][rg];
}

// ---------------- K4: out = relu( sum_s num / sum_s den ) -----------------
__global__ __launch_bounds__(256) void k4_out(const float* __restrict__ num,
                                              const float* __restrict__ den,
                                              float* __restrict__ out) {
    size_t f4 = (size_t)blockIdx.x * 256 + threadIdx.x;
    int i = (int)(f4 >> 6);
    int c4 = (int)(f4 & 63) << 2;
    float4 s = make_float4(0.f, 0.f, 0.f, 0.f);
    float d = 0.f;
    #pragma unroll
    for (int sg = 0; sg < SS; ++sg) {
        float4 v = *(const float4*)&num[((size_t)sg * NN + i) * FF + c4];
        s.x += v.x; s.y += v.y; s.z += v.z; s.w += v.w;
        d += den[(size_t)sg * NN + i];
    }
    float inv = 1.f / d;
    float4 o;
    o.x = fmaxf(s.x * inv, 0.f);
    o.y = fmaxf(s.y * inv, 0.f);
    o.z = fmaxf(s.z * inv, 0.f);
    o.w = fmaxf(s.w * inv, 0.f);
    *(float4*)&out[(size_t)i * FF + c4] = o;
}

extern "C" void kernel_launch(void* const* d_in, const int* in_sizes, int n_in,
                              void* d_out, int out_size, void* d_ws, size_t ws_size,
                              hipStream_t stream) {
    const float* X  = (const float*)d_in[0];
    const int*  adj = (const int*)d_in[1];
    const float* W  = (const float*)d_in[2];
    const float* a  = (const float*)d_in[3];
    float* out = (float*)d_out;
    char* ws = (char*)d_ws;

    const size_t off_hT   = 0;                                  // hi only: 4 MB
    const size_t off_wt   = off_hT + (size_t)FF * NN * 2;
    const size_t off_src  = off_wt + (size_t)2 * FF * FF * 2;
    const size_t off_dst  = off_src + (size_t)NN * 4;
    const size_t off_maxd = off_dst + (size_t)NN * 4;
    const size_t off_num  = off_maxd + 256;
    const size_t off_den  = off_num + (size_t)SS * NN * FF * 4;
    const size_t off_bits = off_den + (size_t)SS * NN * 4;

    __bf16* hT_ws = (__bf16*)(ws + off_hT);
    __bf16* wt_ws = (__bf16*)(ws + off_wt);
    float* src_ws = (float*)(ws + off_src);
    float* dst_ws = (float*)(ws + off_dst);
    unsigned* maxd = (unsigned*)(ws + off_maxd);
    float* num_ws = (float*)(ws + off_num);
    float* den_ws = (float*)(ws + off_den);
    unsigned* bits_ws = (unsigned*)(ws + off_bits);

    k02a<<<2064, 256, 0, stream>>>(W, wt_ws, adj, bits_ws, maxd);
    k1_h<<<NN / 32, 256, 0, stream>>>(X, wt_ws, a, hT_ws, src_ws, dst_ws, maxd);
    k3_attn<<<(NN / BI) * SS, 512, 0, stream>>>(bits_ws, hT_ws, src_ws, dst_ws, maxd,
                                                num_ws, den_ws);
    k4_out<<<(NN * FF / 4) / 256, 256, 0, stream>>>(num_ws, den_ws, out);
}